// Round 1
// baseline (12017.916 us; speedup 1.0000x reference)
//
#include <hip/hip_runtime.h>

// BI-LSTM (TF LSTMCell w/ projection), T=160 B=640 F=40 HID=768 PROJ=256, 3 layers x 2 dirs.
// Strategy R1: per-step MFMA fp16 GEMM kernels (fp32 accum/state), fw+bw fused via blockIdx.z.
// Gate columns of Wk are pre-permuted to interleave (i,j,f,o) per hidden unit so each 64-col
// block epilogue owns all 4 gates for 16 units -> c-update fused into the z-GEMM kernel.

typedef _Float16 h8 __attribute__((ext_vector_type(8)));
typedef float f4 __attribute__((ext_vector_type(4)));

#define T_STEPS 160
#define NB 640
#define HID 768
#define PROJ 256
#define NGATE 3072           // 4*HID
#define LSTRIDE 72           // LDS row stride in halves: 144B = 16B-aligned, 2-way-bank-free

__device__ __forceinline__ float sigm(float x) { return 1.0f / (1.0f + __expf(-x)); }
__device__ __forceinline__ float tanh_fast(float x) { return 2.0f / (1.0f + __expf(-2.0f * x)) - 1.0f; }

// ---------------- GEMM step kernel ----------------
// C[m0..m0+64, n0..n0+64] = A[m,:] @ B^T[n,:],  A = concat(A0 (width w0), A1 (width 256, h-src))
// MODE 1: gate epilogue (bias add, i/j/f/o interleaved cols, c-update, write g fp16)
// MODE 0: plain fp16 store to outp (projection h = g @ WpT)
template<int MODE>
__global__ __launch_bounds__(256) void gemm_step(
    const _Float16* __restrict__ A0f, const _Float16* __restrict__ A0b,
    int w0, int lda0,
    const _Float16* __restrict__ A1f, const _Float16* __restrict__ A1b,
    const _Float16* __restrict__ Bwf, const _Float16* __restrict__ Bwb, int K,
    const float* __restrict__ biasf, const float* __restrict__ biasb,
    float* __restrict__ cstate, _Float16* __restrict__ gbuf,
    _Float16* __restrict__ outf, _Float16* __restrict__ outb, int N)
{
  __shared__ __align__(16) _Float16 As[64][LSTRIDE];
  __shared__ __align__(16) _Float16 Bs[64][LSTRIDE];
  __shared__ __align__(16) float zs[64][68];   // only used in MODE 1

  const int d = blockIdx.z;
  const _Float16* A0 = d ? A0b : A0f;
  const _Float16* A1 = d ? A1b : A1f;
  const _Float16* Bw = d ? Bwb : Bwf;
  const int n0 = blockIdx.x * 64;
  const int m0 = blockIdx.y * 64;
  const int tid = threadIdx.x;
  const int lane = tid & 63;
  const int wv = tid >> 6;
  const int wm = (wv & 1) * 32;   // wave's 32x32 quadrant
  const int wn = (wv >> 1) * 32;

  f4 acc[2][2] = {};

  const int lr = tid >> 3;          // 0..31 (rows lr and lr+32)
  const int lkg = (tid & 7) * 8;    // k-group 0,8,..,56

  for (int k0 = 0; k0 < K; k0 += 64) {
    const int gk = k0 + lkg;
    h8 av0, av1;
    if (gk < w0) {
      av0 = *(const h8*)(A0 + (size_t)(m0 + lr) * lda0 + gk);
      av1 = *(const h8*)(A0 + (size_t)(m0 + lr + 32) * lda0 + gk);
    } else {
      av0 = *(const h8*)(A1 + (size_t)(m0 + lr) * 256 + (gk - w0));
      av1 = *(const h8*)(A1 + (size_t)(m0 + lr + 32) * 256 + (gk - w0));
    }
    h8 bv0 = *(const h8*)(Bw + (size_t)(n0 + lr) * K + gk);
    h8 bv1 = *(const h8*)(Bw + (size_t)(n0 + lr + 32) * K + gk);
    __syncthreads();
    *(h8*)&As[lr][lkg] = av0;
    *(h8*)&As[lr + 32][lkg] = av1;
    *(h8*)&Bs[lr][lkg] = bv0;
    *(h8*)&Bs[lr + 32][lkg] = bv1;
    __syncthreads();
    const int mr = wm + (lane & 15);
    const int nr = wn + (lane & 15);
#pragma unroll
    for (int kk = 0; kk < 2; ++kk) {
      const int kq = ((lane >> 4) * 8) + kk * 32;
      h8 a0 = *(const h8*)&As[mr][kq];
      h8 a1 = *(const h8*)&As[mr + 16][kq];
      h8 b0 = *(const h8*)&Bs[nr][kq];
      h8 b1 = *(const h8*)&Bs[nr + 16][kq];
      acc[0][0] = __builtin_amdgcn_mfma_f32_16x16x32_f16(a0, b0, acc[0][0], 0, 0, 0);
      acc[0][1] = __builtin_amdgcn_mfma_f32_16x16x32_f16(a0, b1, acc[0][1], 0, 0, 0);
      acc[1][0] = __builtin_amdgcn_mfma_f32_16x16x32_f16(a1, b0, acc[1][0], 0, 0, 0);
      acc[1][1] = __builtin_amdgcn_mfma_f32_16x16x32_f16(a1, b1, acc[1][1], 0, 0, 0);
    }
  }

  if (MODE == 0) {
    _Float16* outp = d ? outb : outf;
#pragma unroll
    for (int mi = 0; mi < 2; ++mi)
#pragma unroll
      for (int ni = 0; ni < 2; ++ni)
#pragma unroll
        for (int r = 0; r < 4; ++r) {
          int row = wm + mi * 16 + ((lane >> 4) << 2) + r;  // C/D: row=(lane>>4)*4+reg
          int col = wn + ni * 16 + (lane & 15);             //      col=lane&15
          outp[(size_t)(m0 + row) * N + (n0 + col)] = (_Float16)acc[mi][ni][r];
        }
  } else {
#pragma unroll
    for (int mi = 0; mi < 2; ++mi)
#pragma unroll
      for (int ni = 0; ni < 2; ++ni)
#pragma unroll
        for (int r = 0; r < 4; ++r) {
          int row = wm + mi * 16 + ((lane >> 4) << 2) + r;
          int col = wn + ni * 16 + (lane & 15);
          zs[row][col] = acc[mi][ni][r];
        }
    __syncthreads();
    const float* bias = d ? biasb : biasf;
    const int u0 = n0 >> 2;  // first hidden unit of this block (16 units/block)
#pragma unroll
    for (int it = 0; it < 4; ++it) {
      int item = it * 256 + tid;      // 64 rows x 16 units
      int row = item >> 4;
      int u = item & 15;
      float zi = zs[row][4 * u + 0] + bias[0 * HID + u0 + u];
      float zj = zs[row][4 * u + 1] + bias[1 * HID + u0 + u];
      float zf = zs[row][4 * u + 2] + bias[2 * HID + u0 + u];
      float zo = zs[row][4 * u + 3] + bias[3 * HID + u0 + u];
      size_t co = ((size_t)d * NB + (m0 + row)) * HID + u0 + u;
      float cold = cstate[co];
      float cnew = sigm(zf + 1.0f) * cold + sigm(zi) * tanh_fast(zj);  // forget_bias=1.0
      float g = sigm(zo) * tanh_fast(cnew);
      cstate[co] = cnew;
      gbuf[co] = (_Float16)g;
    }
  }
}

// ---------------- prep kernels ----------------
// X fp32 [160,640,40] -> fp16 [160,640,64] zero-padded
__global__ void convX(const float* __restrict__ X, _Float16* __restrict__ X16, size_t total) {
  size_t i = (size_t)blockIdx.x * 256 + threadIdx.x;
  if (i >= total) return;
  int p = (int)(i & 63);
  size_t tb = i >> 6;
  float v = (p < 40) ? X[tb * 40 + p] : 0.0f;
  X16[i] = (_Float16)v;
}

// Wk fp32 [Kin+256, 3072] -> WkT fp16 [3072][Kpad], gate-interleaved rows n'=4u+g,
// layer0 k-map: k<40 -> Wk[k]; 40..63 -> 0; 64..319 -> Wk[k-24]
__global__ void conv_wk(const float* __restrict__ Wk, _Float16* __restrict__ out,
                        int mode, int Kpad, size_t total) {
  size_t i = (size_t)blockIdx.x * 256 + threadIdx.x;
  if (i >= total) return;
  int k = (int)(i % Kpad);
  int n = (int)(i / Kpad);
  int u = n >> 2, g = n & 3;
  int col = g * HID + u;
  float v;
  if (mode == 0) {
    if (k < 40)      v = Wk[(size_t)k * NGATE + col];
    else if (k < 64) v = 0.0f;
    else             v = Wk[(size_t)(k - 24) * NGATE + col];
  } else {
    v = Wk[(size_t)k * NGATE + col];
  }
  out[i] = (_Float16)v;
}

// Wp fp32 [768,256] -> WpT fp16 [256][768]
__global__ void conv_wp(const float* __restrict__ Wp, _Float16* __restrict__ out, size_t total) {
  size_t i = (size_t)blockIdx.x * 256 + threadIdx.x;
  if (i >= total) return;
  int k = (int)(i % HID);
  int c = (int)(i / HID);
  out[i] = (_Float16)Wp[(size_t)k * PROJ + c];
}

// ---------------- readout ----------------
// e[b, 0:256]=(fw[t=0]+fw[t=159])/2, e[b,256:512]=(bw[0]+bw[159])/2, L2-normalize over 512
__global__ __launch_bounds__(256) void readout(const _Float16* __restrict__ Y, float* __restrict__ out) {
  const size_t SL = (size_t)NB * PROJ;
  const size_t DD = 162UL * SL;
  int b = blockIdx.x, tid = threadIdx.x;
  float v[2];
  float ss = 0.0f;
#pragma unroll
  for (int i = 0; i < 2; ++i) {
    int j = tid + i * 256;
    int d = j >> 8, c = j & 255;
    const _Float16* base = Y + (size_t)d * DD;
    float a = (float)base[SL + (size_t)b * PROJ + c];          // slot 1  = time 0
    float z = (float)base[160 * SL + (size_t)b * PROJ + c];    // slot 160 = time 159
    v[i] = 0.5f * (a + z);
    ss += v[i] * v[i];
  }
#pragma unroll
  for (int off = 32; off; off >>= 1) ss += __shfl_down(ss, off);
  __shared__ float ps[4];
  if ((tid & 63) == 0) ps[tid >> 6] = ss;
  __syncthreads();
  float tot = ps[0] + ps[1] + ps[2] + ps[3];
  float nrm = rsqrtf(fmaxf(tot, 1e-12f));
  out[(size_t)b * 512 + tid] = v[0] * nrm;
  out[(size_t)b * 512 + tid + 256] = v[1] * nrm;
}

extern "C" void kernel_launch(void* const* d_in, const int* in_sizes, int n_in,
                              void* d_out, int out_size, void* d_ws, size_t ws_size,
                              hipStream_t stream) {
  (void)in_sizes; (void)n_in; (void)out_size; (void)ws_size;
  const float* X = (const float*)d_in[0];
  const float* Wk[2][3]; const float* Bi[2][3]; const float* Wp[2][3];
  for (int d = 0; d < 2; ++d)
    for (int l = 0; l < 3; ++l) {
      int base = 1 + d * 9 + l * 3;
      Wk[d][l] = (const float*)d_in[base];
      Bi[d][l] = (const float*)d_in[base + 1];
      Wp[d][l] = (const float*)d_in[base + 2];
    }

  char* ws = (char*)d_ws;
  size_t off = 0;
  auto alloc = [&](size_t bytes) -> void* {
    void* p = ws + off;
    off += (bytes + 255) & ~(size_t)255;
    return p;
  };

  const size_t SL = (size_t)NB * PROJ;        // halves per time-slot
  const size_t DD = 162UL * SL;               // halves per direction (slots 0..161)

  _Float16* X16 = (_Float16*)alloc((size_t)T_STEPS * NB * 64 * 2);
  _Float16* WkT[2][3];
  for (int d = 0; d < 2; ++d)
    for (int l = 0; l < 3; ++l)
      WkT[d][l] = (_Float16*)alloc((size_t)NGATE * (l == 0 ? 320 : 512) * 2);
  _Float16* WpT[2][3];
  for (int d = 0; d < 2; ++d)
    for (int l = 0; l < 3; ++l)
      WpT[d][l] = (_Float16*)alloc((size_t)PROJ * HID * 2);
  _Float16* Yb[2];
  Yb[0] = (_Float16*)alloc(2UL * DD * 2);
  Yb[1] = (_Float16*)alloc(2UL * DD * 2);
  float* cst = (float*)alloc(2UL * NB * HID * 4);
  _Float16* gbuf = (_Float16*)alloc(2UL * NB * HID * 2);

  // ---- prep ----
  {
    size_t tot = (size_t)T_STEPS * NB * 64;
    convX<<<dim3((unsigned)((tot + 255) / 256)), 256, 0, stream>>>(X, X16, tot);
  }
  for (int d = 0; d < 2; ++d)
    for (int l = 0; l < 3; ++l) {
      int Kpad = (l == 0) ? 320 : 512;
      size_t tot = (size_t)NGATE * Kpad;
      conv_wk<<<dim3((unsigned)((tot + 255) / 256)), 256, 0, stream>>>(
          Wk[d][l], WkT[d][l], (l == 0) ? 0 : 1, Kpad, tot);
      size_t totp = (size_t)PROJ * HID;
      conv_wp<<<dim3((unsigned)((totp + 255) / 256)), 256, 0, stream>>>(Wp[d][l], WpT[d][l], totp);
    }
  // zero h-init slots (0 and 161) in both ping-pong buffers, both directions
  for (int buf = 0; buf < 2; ++buf)
    for (int d = 0; d < 2; ++d) {
      hipMemsetAsync((char*)Yb[buf] + ((size_t)d * DD + 0 * SL) * 2, 0, SL * 2, stream);
      hipMemsetAsync((char*)Yb[buf] + ((size_t)d * DD + 161 * SL) * 2, 0, SL * 2, stream);
    }

  // ---- layers ----
  for (int l = 0; l < 3; ++l) {
    hipMemsetAsync(cst, 0, 2UL * NB * HID * 4, stream);
    _Float16* Ycur = Yb[l & 1];
    _Float16* Yprev = (l == 0) ? nullptr : Yb[(l + 1) & 1];
    int K = (l == 0) ? 320 : 512;
    int w0 = (l == 0) ? 64 : 256;
    int lda0 = w0;
    for (int s = 0; s < T_STEPS; ++s) {
      int tf = s, tb = 159 - s;
      const _Float16 *A0f, *A0b;
      if (l == 0) {
        A0f = X16 + (size_t)tf * NB * 64;
        A0b = X16 + (size_t)tb * NB * 64;
      } else {
        A0f = Yprev + 0 * DD + (size_t)(tf + 1) * SL;   // x_t = prev-layer output, slot t+1
        A0b = Yprev + 1 * DD + (size_t)(tb + 1) * SL;
      }
      const _Float16* A1f = Ycur + 0 * DD + (size_t)tf * SL;        // h_{t-1}: slot t
      const _Float16* A1b = Ycur + 1 * DD + (size_t)(tb + 2) * SL;  // h_{t+1}: slot t+2
      gemm_step<1><<<dim3(48, 10, 2), 256, 0, stream>>>(
          A0f, A0b, w0, lda0, A1f, A1b,
          WkT[0][l], WkT[1][l], K, Bi[0][l], Bi[1][l],
          cst, gbuf, nullptr, nullptr, NGATE);
      _Float16* of = Ycur + 0 * DD + (size_t)(tf + 1) * SL;
      _Float16* ob = Ycur + 1 * DD + (size_t)(tb + 1) * SL;
      gemm_step<0><<<dim3(4, 10, 2), 256, 0, stream>>>(
          gbuf, gbuf + (size_t)NB * HID, 1 << 30, HID, nullptr, nullptr,
          WpT[0][l], WpT[1][l], HID, nullptr, nullptr,
          nullptr, nullptr, of, ob, PROJ);
    }
  }

  // layer 2 wrote into Yb[0]
  readout<<<dim3(NB), 256, 0, stream>>>(Yb[0], (float*)d_out);
}

// Round 2
// 6124.281 us; speedup vs baseline: 1.9623x; 1.9623x over previous
//
#include <hip/hip_runtime.h>

// BI-LSTM (TF LSTMCell w/ projection), T=160 B=640 F=40 HID=768 PROJ=256, 3 layers x 2 dirs.
// R2: layer-wavefront pipeline. Super-step s computes (layer l, progress t=s-l) for all l,
// both directions, in ONE gate launch (grid z=6) + ONE proj launch. h-history lives in
// 4-slot ring buffers per (l,d) (pipeline slack is 1 super-step). Gate tile 128x64 (8 waves),
// LDS union'd with epilogue scratch. Launch count ~340 vs R1's ~1950.

typedef _Float16 h8 __attribute__((ext_vector_type(8)));
typedef float f4 __attribute__((ext_vector_type(4)));

#define T_STEPS 160
#define NB 640
#define HID 768
#define PROJ 256
#define NGATE 3072           // 4*HID

__device__ __forceinline__ float sigm(float x) { return 1.0f / (1.0f + __expf(-x)); }
__device__ __forceinline__ float tanh_fast(float x) { return 2.0f / (1.0f + __expf(-2.0f * x)) - 1.0f; }

struct GateArgs {
  const _Float16* A0[6];   // x-part source (X16 for l=0, prev-layer ring slot otherwise)
  const _Float16* A1[6];   // own h ring slot (h_{t-1} fw / h_{t+1} bw)
  const _Float16* Bw[6];   // WkT, gate-interleaved [3072][Kpad]
  const float*    bias[6];
  float*          cst[6];
  _Float16*       g[6];
  int w0[6];
  int lda0[6];
  int K[6];
  int act[6];
};

struct ProjArgs {
  const _Float16* G[6];    // [640][768] fp16
  const _Float16* Wp[6];   // [256][768] fp16 (B^T)
  _Float16* out[6];        // own ring write slot
  _Float16* out2[6];       // optional embed capture (layer 2, t in {0,159})
  int act[6];
};

// ---------------- gate GEMM: z = [x,h] @ WkT^T, fused bias+gates+c-update -> g ----------------
// 128x64 tile, 512 threads (8 waves of 32x32 quadrants). Gate cols pre-interleaved (i,j,f,o)
// per hidden unit: each 64-col block owns complete gates for 16 units.
__global__ __launch_bounds__(512) void gate_step(GateArgs args) {
  const int z = blockIdx.z;
  if (!args.act[z]) return;

  __shared__ __align__(16) char sm[33280];             // max(As+Bs=27648, zs=33280)
  _Float16 (*As)[72] = (_Float16(*)[72])sm;            // [128][72]
  _Float16 (*Bs)[72] = (_Float16(*)[72])(sm + 18432);  // [64][72]
  float (*zs)[65] = (float(*)[65])sm;                  // [128][65]

  const _Float16* A0 = args.A0[z];
  const _Float16* A1 = args.A1[z];
  const _Float16* Bw = args.Bw[z];
  const int w0 = args.w0[z], lda0 = args.lda0[z], K = args.K[z];
  const int n0 = blockIdx.x * 64;
  const int m0 = blockIdx.y * 128;
  const int tid = threadIdx.x;
  const int lane = tid & 63;
  const int wv = tid >> 6;
  const int wm = (wv & 3) * 32;
  const int wn = (wv >> 2) * 32;

  f4 acc[2][2] = {};

  const int lr = tid >> 3;          // 0..63
  const int lkg = (tid & 7) * 8;    // k-group 0,8,..,56

  for (int k0 = 0; k0 < K; k0 += 64) {
    const int gk = k0 + lkg;
    h8 av0, av1;
    if (gk < w0) {
      av0 = *(const h8*)(A0 + (size_t)(m0 + lr) * lda0 + gk);
      av1 = *(const h8*)(A0 + (size_t)(m0 + lr + 64) * lda0 + gk);
    } else {
      av0 = *(const h8*)(A1 + (size_t)(m0 + lr) * 256 + (gk - w0));
      av1 = *(const h8*)(A1 + (size_t)(m0 + lr + 64) * 256 + (gk - w0));
    }
    h8 bv = *(const h8*)(Bw + (size_t)(n0 + lr) * K + gk);
    __syncthreads();
    *(h8*)&As[lr][lkg] = av0;
    *(h8*)&As[lr + 64][lkg] = av1;
    *(h8*)&Bs[lr][lkg] = bv;
    __syncthreads();
    const int mr = wm + (lane & 15);
    const int nr = wn + (lane & 15);
#pragma unroll
    for (int kk = 0; kk < 2; ++kk) {
      const int kq = ((lane >> 4) * 8) + kk * 32;
      h8 a0 = *(const h8*)&As[mr][kq];
      h8 a1 = *(const h8*)&As[mr + 16][kq];
      h8 b0 = *(const h8*)&Bs[nr][kq];
      h8 b1 = *(const h8*)&Bs[nr + 16][kq];
      acc[0][0] = __builtin_amdgcn_mfma_f32_16x16x32_f16(a0, b0, acc[0][0], 0, 0, 0);
      acc[0][1] = __builtin_amdgcn_mfma_f32_16x16x32_f16(a0, b1, acc[0][1], 0, 0, 0);
      acc[1][0] = __builtin_amdgcn_mfma_f32_16x16x32_f16(a1, b0, acc[1][0], 0, 0, 0);
      acc[1][1] = __builtin_amdgcn_mfma_f32_16x16x32_f16(a1, b1, acc[1][1], 0, 0, 0);
    }
  }

  __syncthreads();   // protect As/Bs before aliasing as zs
#pragma unroll
  for (int mi = 0; mi < 2; ++mi)
#pragma unroll
    for (int ni = 0; ni < 2; ++ni)
#pragma unroll
      for (int r = 0; r < 4; ++r) {
        int row = wm + mi * 16 + ((lane >> 4) << 2) + r;  // C/D: row=(lane>>4)*4+reg
        int col = wn + ni * 16 + (lane & 15);             //      col=lane&15
        zs[row][col] = acc[mi][ni][r];
      }
  __syncthreads();

  const float* bias = args.bias[z];
  float* cstate = args.cst[z];
  _Float16* gout = args.g[z];
  const int u0 = n0 >> 2;  // first hidden unit of this block (16 units/block)
#pragma unroll
  for (int it = 0; it < 4; ++it) {
    int item = it * 512 + tid;      // 128 rows x 16 units
    int row = item >> 4;
    int u = item & 15;
    float zi = zs[row][4 * u + 0] + bias[0 * HID + u0 + u];
    float zj = zs[row][4 * u + 1] + bias[1 * HID + u0 + u];
    float zf = zs[row][4 * u + 2] + bias[2 * HID + u0 + u];
    float zo = zs[row][4 * u + 3] + bias[3 * HID + u0 + u];
    size_t co = (size_t)(m0 + row) * HID + u0 + u;
    float cold = cstate[co];
    float cnew = sigm(zf + 1.0f) * cold + sigm(zi) * tanh_fast(zj);  // forget_bias=1.0
    float g = sigm(zo) * tanh_fast(cnew);
    cstate[co] = cnew;
    gout[co] = (_Float16)g;
  }
}

// ---------------- projection GEMM: h = g @ WpT^T ----------------
// 64x64 tile, 256 threads, K=768.
__global__ __launch_bounds__(256) void proj_step(ProjArgs args) {
  const int z = blockIdx.z;
  if (!args.act[z]) return;

  __shared__ __align__(16) _Float16 As[64][72];
  __shared__ __align__(16) _Float16 Bs[64][72];

  const _Float16* A = args.G[z];
  const _Float16* B = args.Wp[z];
  const int n0 = blockIdx.x * 64;
  const int m0 = blockIdx.y * 64;
  const int tid = threadIdx.x;
  const int lane = tid & 63;
  const int wv = tid >> 6;
  const int wm = (wv & 1) * 32;
  const int wn = (wv >> 1) * 32;

  f4 acc[2][2] = {};
  const int lr = tid >> 3;
  const int lkg = (tid & 7) * 8;

  for (int k0 = 0; k0 < HID; k0 += 64) {
    const int gk = k0 + lkg;
    h8 av0 = *(const h8*)(A + (size_t)(m0 + lr) * HID + gk);
    h8 av1 = *(const h8*)(A + (size_t)(m0 + lr + 32) * HID + gk);
    h8 bv0 = *(const h8*)(B + (size_t)(n0 + lr) * HID + gk);
    h8 bv1 = *(const h8*)(B + (size_t)(n0 + lr + 32) * HID + gk);
    __syncthreads();
    *(h8*)&As[lr][lkg] = av0;
    *(h8*)&As[lr + 32][lkg] = av1;
    *(h8*)&Bs[lr][lkg] = bv0;
    *(h8*)&Bs[lr + 32][lkg] = bv1;
    __syncthreads();
    const int mr = wm + (lane & 15);
    const int nr = wn + (lane & 15);
#pragma unroll
    for (int kk = 0; kk < 2; ++kk) {
      const int kq = ((lane >> 4) * 8) + kk * 32;
      h8 a0 = *(const h8*)&As[mr][kq];
      h8 a1 = *(const h8*)&As[mr + 16][kq];
      h8 b0 = *(const h8*)&Bs[nr][kq];
      h8 b1 = *(const h8*)&Bs[nr + 16][kq];
      acc[0][0] = __builtin_amdgcn_mfma_f32_16x16x32_f16(a0, b0, acc[0][0], 0, 0, 0);
      acc[0][1] = __builtin_amdgcn_mfma_f32_16x16x32_f16(a0, b1, acc[0][1], 0, 0, 0);
      acc[1][0] = __builtin_amdgcn_mfma_f32_16x16x32_f16(a1, b0, acc[1][0], 0, 0, 0);
      acc[1][1] = __builtin_amdgcn_mfma_f32_16x16x32_f16(a1, b1, acc[1][1], 0, 0, 0);
    }
  }

  _Float16* outp = args.out[z];
  _Float16* out2 = args.out2[z];
#pragma unroll
  for (int mi = 0; mi < 2; ++mi)
#pragma unroll
    for (int ni = 0; ni < 2; ++ni)
#pragma unroll
      for (int r = 0; r < 4; ++r) {
        int row = wm + mi * 16 + ((lane >> 4) << 2) + r;
        int col = wn + ni * 16 + (lane & 15);
        _Float16 v = (_Float16)acc[mi][ni][r];
        size_t o = (size_t)(m0 + row) * PROJ + (n0 + col);
        outp[o] = v;
        if (out2) out2[o] = v;
      }
}

// ---------------- prep kernels ----------------
__global__ void convX(const float* __restrict__ X, _Float16* __restrict__ X16, size_t total) {
  size_t i = (size_t)blockIdx.x * 256 + threadIdx.x;
  if (i >= total) return;
  int p = (int)(i & 63);
  size_t tb = i >> 6;
  float v = (p < 40) ? X[tb * 40 + p] : 0.0f;
  X16[i] = (_Float16)v;
}

// Wk fp32 [Kin+256, 3072] -> WkT fp16 [3072][Kpad], gate-interleaved rows n'=4u+g,
// layer0 k-map: k<40 -> Wk[k]; 40..63 -> 0; 64..319 -> Wk[k-24]
__global__ void conv_wk(const float* __restrict__ Wk, _Float16* __restrict__ out,
                        int mode, int Kpad, size_t total) {
  size_t i = (size_t)blockIdx.x * 256 + threadIdx.x;
  if (i >= total) return;
  int k = (int)(i % Kpad);
  int n = (int)(i / Kpad);
  int u = n >> 2, g = n & 3;
  int col = g * HID + u;
  float v;
  if (mode == 0) {
    if (k < 40)      v = Wk[(size_t)k * NGATE + col];
    else if (k < 64) v = 0.0f;
    else             v = Wk[(size_t)(k - 24) * NGATE + col];
  } else {
    v = Wk[(size_t)k * NGATE + col];
  }
  out[i] = (_Float16)v;
}

__global__ void conv_wp(const float* __restrict__ Wp, _Float16* __restrict__ out, size_t total) {
  size_t i = (size_t)blockIdx.x * 256 + threadIdx.x;
  if (i >= total) return;
  int k = (int)(i % HID);
  int c = (int)(i / HID);
  out[i] = (_Float16)Wp[(size_t)k * PROJ + c];
}

// ---------------- readout ----------------
// embed buffer E[d][which][640][256] fp16, which: 0 = t=0, 1 = t=159.
__global__ __launch_bounds__(256) void readout(const _Float16* __restrict__ E, float* __restrict__ out) {
  const size_t SL = (size_t)NB * PROJ;
  int b = blockIdx.x, tid = threadIdx.x;
  float v[2];
  float ss = 0.0f;
#pragma unroll
  for (int i = 0; i < 2; ++i) {
    int j = tid + i * 256;
    int d = j >> 8, c = j & 255;
    const _Float16* base = E + (size_t)d * 2 * SL;
    float a = (float)base[(size_t)b * PROJ + c];
    float z = (float)base[SL + (size_t)b * PROJ + c];
    v[i] = 0.5f * (a + z);
    ss += v[i] * v[i];
  }
#pragma unroll
  for (int off = 32; off; off >>= 1) ss += __shfl_down(ss, off);
  __shared__ float ps[4];
  if ((tid & 63) == 0) ps[tid >> 6] = ss;
  __syncthreads();
  float tot = ps[0] + ps[1] + ps[2] + ps[3];
  float nrm = rsqrtf(fmaxf(tot, 1e-12f));
  out[(size_t)b * 512 + tid] = v[0] * nrm;
  out[(size_t)b * 512 + tid + 256] = v[1] * nrm;
}

extern "C" void kernel_launch(void* const* d_in, const int* in_sizes, int n_in,
                              void* d_out, int out_size, void* d_ws, size_t ws_size,
                              hipStream_t stream) {
  (void)in_sizes; (void)n_in; (void)out_size; (void)ws_size;
  const float* X = (const float*)d_in[0];
  const float* Wk[2][3]; const float* Bi[2][3]; const float* Wp[2][3];
  for (int d = 0; d < 2; ++d)
    for (int l = 0; l < 3; ++l) {
      int base = 1 + d * 9 + l * 3;
      Wk[d][l] = (const float*)d_in[base];
      Bi[d][l] = (const float*)d_in[base + 1];
      Wp[d][l] = (const float*)d_in[base + 2];
    }

  char* ws = (char*)d_ws;
  size_t off = 0;
  auto alloc = [&](size_t bytes) -> void* {
    void* p = ws + off;
    off += (bytes + 255) & ~(size_t)255;
    return p;
  };

  const size_t SL = (size_t)NB * PROJ;    // halves per time-slot

  _Float16* X16 = (_Float16*)alloc((size_t)T_STEPS * NB * 64 * 2);
  _Float16* WkT[2][3];
  for (int d = 0; d < 2; ++d)
    for (int l = 0; l < 3; ++l)
      WkT[d][l] = (_Float16*)alloc((size_t)NGATE * (l == 0 ? 320 : 512) * 2);
  _Float16* WpT[2][3];
  for (int d = 0; d < 2; ++d)
    for (int l = 0; l < 3; ++l)
      WpT[d][l] = (_Float16*)alloc((size_t)PROJ * HID * 2);
  _Float16* Hbuf = (_Float16*)alloc(6UL * 4 * SL * 2);      // [l*2+d][4 slots][640][256]
  float* cst = (float*)alloc(6UL * NB * HID * 4);
  _Float16* gbuf = (_Float16*)alloc(6UL * NB * HID * 2);
  _Float16* embed = (_Float16*)alloc(4UL * SL * 2);         // [d][which][640][256]

  auto Hslot = [&](int l, int d, int slot) -> _Float16* {
    return Hbuf + (((size_t)(l * 2 + d) * 4) + slot) * SL;
  };

  // ---- prep ----
  {
    size_t tot = (size_t)T_STEPS * NB * 64;
    convX<<<dim3((unsigned)((tot + 255) / 256)), 256, 0, stream>>>(X, X16, tot);
  }
  for (int d = 0; d < 2; ++d)
    for (int l = 0; l < 3; ++l) {
      int Kpad = (l == 0) ? 320 : 512;
      size_t tot = (size_t)NGATE * Kpad;
      conv_wk<<<dim3((unsigned)((tot + 255) / 256)), 256, 0, stream>>>(
          Wk[d][l], WkT[d][l], (l == 0) ? 0 : 1, Kpad, tot);
      size_t totp = (size_t)PROJ * HID;
      conv_wp<<<dim3((unsigned)((totp + 255) / 256)), 256, 0, stream>>>(Wp[d][l], WpT[d][l], totp);
    }
  hipMemsetAsync(Hbuf, 0, 6UL * 4 * SL * 2, stream);        // zero rings (incl. h-init slots)
  hipMemsetAsync(cst, 0, 6UL * NB * HID * 4, stream);       // zero c state

  // ---- pipelined super-steps ----
  for (int s = 0; s <= 161; ++s) {
    GateArgs ga{};
    ProjArgs pa{};
    for (int l = 0; l < 3; ++l)
      for (int d = 0; d < 2; ++d) {
        int z = l * 2 + d;
        int t = s - l;                        // progress of layer l
        if (t < 0 || t > 159) { ga.act[z] = 0; pa.act[z] = 0; continue; }
        int tt = (d == 0) ? t : 159 - t;      // actual time index
        ga.act[z] = 1; pa.act[z] = 1;
        if (l == 0) {
          ga.A0[z] = X16 + (size_t)tt * NB * 64;
          ga.w0[z] = 64; ga.lda0[z] = 64; ga.K[z] = 320;
        } else {
          ga.A0[z] = Hslot(l - 1, d, (tt + 1) & 3);   // prev-layer output at time tt
          ga.w0[z] = 256; ga.lda0[z] = 256; ga.K[z] = 512;
        }
        int rdslot = (d == 0) ? (tt & 3) : ((tt + 2) & 3);
        ga.A1[z] = Hslot(l, d, rdslot);
        ga.Bw[z] = WkT[d][l];
        ga.bias[z] = Bi[d][l];
        ga.cst[z] = cst + (size_t)z * NB * HID;
        ga.g[z] = gbuf + (size_t)z * NB * HID;

        pa.G[z] = gbuf + (size_t)z * NB * HID;
        pa.Wp[z] = WpT[d][l];
        pa.out[z] = Hslot(l, d, (tt + 1) & 3);
        pa.out2[z] = nullptr;
        if (l == 2 && (tt == 0 || tt == 159))
          pa.out2[z] = embed + ((size_t)d * 2 + (tt == 0 ? 0 : 1)) * SL;
      }
    gate_step<<<dim3(48, 5, 6), 512, 0, stream>>>(ga);
    proj_step<<<dim3(4, 10, 6), 256, 0, stream>>>(pa);
  }

  readout<<<dim3(NB), 256, 0, stream>>>(embed, (float*)d_out);
}